// Round 6
// baseline (80.148 us; speedup 1.0000x reference)
//
#include <hip/hip_runtime.h>

#define TGS_D 128
#define TGS_E 20
#define TGS_K 10
#define TGS_F1 276               // 2D+E
#define LDA1 296                 // f16 stride for A1 panel
#define LDA2 264                 // f16 stride for A2 panel
#define RPB 16                   // rows per block (one M-tile)

typedef _Float16 f16;
typedef _Float16 f16x4 __attribute__((ext_vector_type(4)));
typedef _Float16 f16x8 __attribute__((ext_vector_type(8)));
typedef float    f32x4 __attribute__((ext_vector_type(4)));

// ---------------- NF -> f16 table (12.8M elems, 8 per thread, 6250 blocks) ----
__global__ __launch_bounds__(256)
void tgs_nf16(const float* __restrict__ NF, f16* __restrict__ NF16) {
    const int i = (blockIdx.x * 256 + threadIdx.x) * 8;
    const float4 a = *(const float4*)(NF + i);
    const float4 b = *(const float4*)(NF + i + 4);
    *(f16x8*)(NF16 + i) = f16x8{(f16)a.x, (f16)a.y, (f16)a.z, (f16)a.w,
                                (f16)b.x, (f16)b.y, (f16)b.z, (f16)b.w};
}

// ---------------- merged setup: pack W1, pack W2, tvec ----------------
__global__ __launch_bounds__(128)
void tgs_setup(const float* __restrict__ W1, const float* __restrict__ W2,
               const float* __restrict__ tb, const float* __restrict__ B2,
               f16x8* __restrict__ PW1, f16x8* __restrict__ PW2,
               float* __restrict__ tvec) {
    const int b = blockIdx.x, tid = threadIdx.x;
    if (b < 144) {
        if (tid < 64) {
            const int layer = b / 72, rem = b % 72, ntile = rem / 9, kk = rem % 9;
            const int colg = ntile * 16 + (tid & 15);
            const int kbase = kk * 32 + (tid >> 4) * 8;
            f16x8 v;
            #pragma unroll
            for (int j = 0; j < 8; ++j) {
                const int k = kbase + j;
                v[j] = (k < TGS_F1) ? (f16)W1[(layer * TGS_F1 + k) * TGS_D + colg] : (f16)0.f;
            }
            PW1[b * 64 + tid] = v;
        }
    } else if (b < 272) {
        if (tid < 64) {
            const int bb = b - 144;
            const int layer = bb / 64, rem = bb % 64, ntile = rem / 8, kk = rem % 8;
            const int colg = ntile * 16 + (tid & 15);
            const int kbase = kk * 32 + (tid >> 4) * 8;
            f16x8 v;
            #pragma unroll
            for (int j = 0; j < 8; ++j) {
                const int k = kbase + j;
                const int w2row = (k < TGS_D) ? k : (k + TGS_D);
                v[j] = (f16)W2[(layer * 3 * TGS_D + w2row) * TGS_D + colg];
            }
            PW2[bb * 64 + tid] = v;
        }
    } else {
        const int l = b - 272, d = tid;
        const float* w = W2 + (l * 3 * TGS_D + TGS_D) * TGS_D;
        float acc = B2[l * TGS_D + d];
        for (int j = 0; j < TGS_D; ++j)
            acc = fmaf(__cosf(tb[j]), w[j * TGS_D + d], acc);
        tvec[l * TGS_D + d] = acc;
    }
}

// ---------------- fused per-level kernel: gather+sum -> MFMA GEMM1 -> MFMA GEMM2 ----
// 256 threads = 4 waves; gather: one row per thread (16 lanes x 16B per row);
// GEMMs: each wave owns 2 N-tiles.
template<int LEVEL>
__global__ __launch_bounds__(256, 6)
void tgs_agg_kernel(
    const f16* __restrict__ NF16, const float* __restrict__ EF,
    const int* __restrict__ src_ids, const float* __restrict__ ts_arr,
    const int* __restrict__ nbr_idx,   // LEVEL1 only
    const int* __restrict__ eidx, const float* __restrict__ etime,
    const float* __restrict__ emb_in,  // LEVEL2 only (f32)
    const float* __restrict__ tw, const float* __restrict__ tb,
    const f16x8* __restrict__ PW1, const float* __restrict__ B1,
    const f16x8* __restrict__ PW2, const float* __restrict__ tvec,
    float* __restrict__ out)
{
    __shared__ f16 snf[RPB][LDA1];     // A1: [nodesum 0:128 | timesum 128:256 | edgesum 256:276 | zero pad 276:288]
    __shared__ f16 sf2[RPB][LDA2];     // A2: [src 0:128 | relusum 128:256 | pad]
    __shared__ int   s_nbr[RPB * TGS_K];
    __shared__ int   s_eid[RPB * TGS_K];
    __shared__ float s_et [RPB * TGS_K];
    __shared__ float s_ts [RPB];

    const int tid = threadIdx.x;
    const int base_row = blockIdx.x * RPB;

    // ---- stage indices / times ----
    if (tid < RPB * TGS_K) {
        if (LEVEL == 1) s_nbr[tid] = nbr_idx[base_row * TGS_K + tid];
        s_eid[tid] = eidx[base_row * TGS_K + tid];
        s_et [tid] = etime[base_row * TGS_K + tid];
    }
    if (tid < RPB)
        s_ts[tid] = (LEVEL == 1) ? ts_arr[(base_row + tid) / TGS_K] : ts_arr[base_row + tid];
    __syncthreads();

    // ---- phase 0: gather + K-sum; one row per thread, dims sub*8..sub*8+7 ----
    {
        const int sub = tid & 15;      // f16x8 slot within 128
        const int r   = tid >> 4;      // 0..15
        const int row = base_row + r;

        // neighbor-embedding K-sum (fp32 accum)
        float a[8] = {0.f, 0.f, 0.f, 0.f, 0.f, 0.f, 0.f, 0.f};
        if (LEVEL == 1) {
            #pragma unroll
            for (int k = 0; k < TGS_K; ++k) {
                const int nb = s_nbr[r * TGS_K + k];
                const f16x8 v = *(const f16x8*)(NF16 + nb * TGS_D + sub * 8);
                #pragma unroll
                for (int j = 0; j < 8; ++j) a[j] += (float)v[j];
            }
        } else {
            #pragma unroll
            for (int k = 0; k < TGS_K; ++k) {
                const float* p = emb_in + (row * TGS_K + k) * TGS_D + sub * 8;
                const float4 u0 = ((const float4*)p)[0];
                const float4 u1 = ((const float4*)p)[1];
                a[0] += u0.x; a[1] += u0.y; a[2] += u0.z; a[3] += u0.w;
                a[4] += u1.x; a[5] += u1.y; a[6] += u1.z; a[7] += u1.w;
            }
        }
        f16x8 av;
        #pragma unroll
        for (int j = 0; j < 8; ++j) av[j] = (f16)a[j];
        *(f16x8*)&snf[r][sub * 8] = av;

        // source features: straight f16 copy
        const int sid = src_ids[row];
        *(f16x8*)&sf2[r][sub * 8] = *(const f16x8*)(NF16 + sid * TGS_D + sub * 8);

        // edge-time-encoding K-sum: cos((ts-et)*w + b)
        const float4 w0 = ((const float4*)tw)[sub * 2];
        const float4 w1 = ((const float4*)tw)[sub * 2 + 1];
        const float4 b0 = ((const float4*)tb)[sub * 2];
        const float4 b1 = ((const float4*)tb)[sub * 2 + 1];
        const float ts = s_ts[r];
        float st[8] = {0.f, 0.f, 0.f, 0.f, 0.f, 0.f, 0.f, 0.f};
        #pragma unroll
        for (int k = 0; k < TGS_K; ++k) {
            const float dt = ts - s_et[r * TGS_K + k];
            st[0] += __cosf(fmaf(dt, w0.x, b0.x));
            st[1] += __cosf(fmaf(dt, w0.y, b0.y));
            st[2] += __cosf(fmaf(dt, w0.z, b0.z));
            st[3] += __cosf(fmaf(dt, w0.w, b0.w));
            st[4] += __cosf(fmaf(dt, w1.x, b1.x));
            st[5] += __cosf(fmaf(dt, w1.y, b1.y));
            st[6] += __cosf(fmaf(dt, w1.z, b1.z));
            st[7] += __cosf(fmaf(dt, w1.w, b1.w));
        }
        f16x8 sv;
        #pragma unroll
        for (int j = 0; j < 8; ++j) sv[j] = (f16)st[j];
        *(f16x8*)&snf[r][TGS_D + sub * 8] = sv;

        // edge-feature K-sum (lanes 0..4); lanes 5..7 zero the pad [276,288)
        if (sub < 5) {
            float4 e = make_float4(0.f, 0.f, 0.f, 0.f);
            #pragma unroll
            for (int k = 0; k < TGS_K; ++k) {
                const int eb = s_eid[r * TGS_K + k];
                const float4 v = ((const float4*)(EF + eb * TGS_E))[sub];
                e.x += v.x; e.y += v.y; e.z += v.z; e.w += v.w;
            }
            *(f16x4*)&snf[r][2 * TGS_D + sub * 4] = f16x4{(f16)e.x, (f16)e.y, (f16)e.z, (f16)e.w};
        } else if (sub < 8) {
            *(f16x4*)&snf[r][2 * TGS_D + sub * 4] =
                f16x4{(f16)0.f, (f16)0.f, (f16)0.f, (f16)0.f};
        }
    }
    __syncthreads();

    const int lane = tid & 63;
    const int w    = tid >> 6;         // wave id, owns N-tiles 2w, 2w+1
    const int ccol = lane & 15;        // C/D col; also A row for A-frag reads
    const int row0 = (lane >> 4) * 4;  // C/D row base

    // ---- GEMM1: h = relu(A1 @ W1 + 10*b1) -> sf2 relusum panel (f16) ----
    {
        f32x4 acc0 = {0.f, 0.f, 0.f, 0.f}, acc1 = acc0;
        const f16* abase = &snf[ccol][(lane >> 4) * 8];
        const int t0 = 2 * w, t1 = 2 * w + 1;
        #pragma unroll
        for (int kk = 0; kk < 9; ++kk) {
            const f16x8 af = *(const f16x8*)(abase + kk * 32);
            const f16x8 b0 = PW1[(t0 * 9 + kk) * 64 + lane];
            const f16x8 b1 = PW1[(t1 * 9 + kk) * 64 + lane];
            acc0 = __builtin_amdgcn_mfma_f32_16x16x32_f16(af, b0, acc0, 0, 0, 0);
            acc1 = __builtin_amdgcn_mfma_f32_16x16x32_f16(af, b1, acc1, 0, 0, 0);
        }
        const float b1v0 = 10.f * B1[t0 * 16 + ccol];
        const float b1v1 = 10.f * B1[t1 * 16 + ccol];
        #pragma unroll
        for (int i = 0; i < 4; ++i) {
            sf2[row0 + i][TGS_D + t0 * 16 + ccol] = (f16)fmaxf(acc0[i] + b1v0, 0.f);
            sf2[row0 + i][TGS_D + t1 * 16 + ccol] = (f16)fmaxf(acc1[i] + b1v1, 0.f);
        }
    }
    __syncthreads();

    // ---- GEMM2: out = A2 @ W2cat + tvec ----
    {
        f32x4 acc0 = {0.f, 0.f, 0.f, 0.f}, acc1 = acc0;
        const f16* abase = &sf2[ccol][(lane >> 4) * 8];
        const int t0 = 2 * w, t1 = 2 * w + 1;
        #pragma unroll
        for (int kk = 0; kk < 8; ++kk) {
            const f16x8 af = *(const f16x8*)(abase + kk * 32);
            const f16x8 b0 = PW2[(t0 * 8 + kk) * 64 + lane];
            const f16x8 b1 = PW2[(t1 * 8 + kk) * 64 + lane];
            acc0 = __builtin_amdgcn_mfma_f32_16x16x32_f16(af, b0, acc0, 0, 0, 0);
            acc1 = __builtin_amdgcn_mfma_f32_16x16x32_f16(af, b1, acc1, 0, 0, 0);
        }
        const float tv0 = tvec[t0 * 16 + ccol];
        const float tv1 = tvec[t1 * 16 + ccol];
        #pragma unroll
        for (int i = 0; i < 4; ++i) {
            out[(base_row + row0 + i) * TGS_D + t0 * 16 + ccol] = acc0[i] + tv0;
            out[(base_row + row0 + i) * TGS_D + t1 * 16 + ccol] = acc1[i] + tv1;
        }
    }
}

extern "C" void kernel_launch(void* const* d_in, const int* in_sizes, int n_in,
                              void* d_out, int out_size, void* d_ws, size_t ws_size,
                              hipStream_t stream) {
    const float* NF   = (const float*)d_in[0];
    const float* EF   = (const float*)d_in[1];
    const int*   SRC  = (const int*)  d_in[2];
    const float* TS   = (const float*)d_in[3];
    const int*   NBR1 = (const int*)  d_in[4];
    const int*   EI1  = (const int*)  d_in[5];
    const float* ET1  = (const float*)d_in[6];
    const int*   NBR2 = (const int*)  d_in[7];
    const int*   EI2  = (const int*)  d_in[8];
    const float* ET2  = (const float*)d_in[9];
    const float* TW   = (const float*)d_in[10];
    const float* TB   = (const float*)d_in[11];
    const float* W1   = (const float*)d_in[12];  // [2,276,128]
    const float* B1   = (const float*)d_in[13];  // [2,128]
    const float* W2   = (const float*)d_in[14];  // [2,384,128]
    const float* B2   = (const float*)d_in[15];  // [2,128]

    // workspace layout (16B-aligned offsets); total ~44.7 MiB
    float* emb1 = (float*)d_ws;                              // 40960*128*4   = 20,971,520 B
    f16*   NF16 = (f16*)((char*)d_ws + 20971520);            // 100000*128*2  = 25,600,000 B
    char*  wsb  = (char*)d_ws + 20971520 + 25600000;
    f16x8* PW1  = (f16x8*)wsb;                               // 147,456 B
    f16x8* PW2  = (f16x8*)(wsb + 147456);                    // 131,072 B
    float* tvec = (float*)(wsb + 147456 + 131072);           // 1,024 B

    tgs_nf16 <<<6250, 256, 0, stream>>>(NF, NF16);           // 12.8M elems / 8 / 256
    tgs_setup<<<274, 128, 0, stream>>>(W1, W2, TB, B2, PW1, PW2, tvec);

    const int n1 = 4096 * TGS_K;   // 40960 level-1 rows
    const int n2 = 4096;

    // Level 1 (layer-0 weights) -> emb1 (f32)
    tgs_agg_kernel<1><<<n1 / RPB, 256, 0, stream>>>(
        NF16, EF, NBR1, TS, NBR2, EI2, ET2, nullptr,
        TW, TB, PW1, B1, PW2, tvec, emb1);

    // Level 2 (layer-1 weights) -> d_out
    tgs_agg_kernel<2><<<n2 / RPB, 256, 0, stream>>>(
        NF16, EF, SRC, TS, nullptr, EI1, ET1, emb1,
        TW, TB,
        PW1 + 8 * 9 * 64, B1 + TGS_D,
        PW2 + 8 * 8 * 64, tvec + TGS_D,
        (float*)d_out);
}

// Round 7
// 73.095 us; speedup vs baseline: 1.0965x; 1.0965x over previous
//
#include <hip/hip_runtime.h>

#define TGS_D 128
#define TGS_E 20
#define TGS_K 10
#define TGS_F1 276               // 2D+E
#define LDA1 296                 // f16 stride for A1 panel
#define LDA2 264                 // f16 stride for A2 panel
#define RPB 16                   // rows per block (one M-tile)

typedef _Float16 f16;
typedef _Float16 f16x4 __attribute__((ext_vector_type(4)));
typedef _Float16 f16x8 __attribute__((ext_vector_type(8)));
typedef float    f32x4 __attribute__((ext_vector_type(4)));

// ---------------- NF -> f16 table (12.8M elems, 8 per thread, 6250 blocks) ----
__global__ __launch_bounds__(256)
void tgs_nf16(const float* __restrict__ NF, f16* __restrict__ NF16) {
    const int i = (blockIdx.x * 256 + threadIdx.x) * 8;
    const float4 a = *(const float4*)(NF + i);
    const float4 b = *(const float4*)(NF + i + 4);
    *(f16x8*)(NF16 + i) = f16x8{(f16)a.x, (f16)a.y, (f16)a.z, (f16)a.w,
                                (f16)b.x, (f16)b.y, (f16)b.z, (f16)b.w};
}

// ---------------- merged setup: pack W1, pack W2, tvec ----------------
__global__ __launch_bounds__(128)
void tgs_setup(const float* __restrict__ W1, const float* __restrict__ W2,
               const float* __restrict__ tb, const float* __restrict__ B2,
               f16x8* __restrict__ PW1, f16x8* __restrict__ PW2,
               float* __restrict__ tvec) {
    const int b = blockIdx.x, tid = threadIdx.x;
    if (b < 144) {
        if (tid < 64) {
            const int layer = b / 72, rem = b % 72, ntile = rem / 9, kk = rem % 9;
            const int colg = ntile * 16 + (tid & 15);
            const int kbase = kk * 32 + (tid >> 4) * 8;
            f16x8 v;
            #pragma unroll
            for (int j = 0; j < 8; ++j) {
                const int k = kbase + j;
                v[j] = (k < TGS_F1) ? (f16)W1[(layer * TGS_F1 + k) * TGS_D + colg] : (f16)0.f;
            }
            PW1[b * 64 + tid] = v;
        }
    } else if (b < 272) {
        if (tid < 64) {
            const int bb = b - 144;
            const int layer = bb / 64, rem = bb % 64, ntile = rem / 8, kk = rem % 8;
            const int colg = ntile * 16 + (tid & 15);
            const int kbase = kk * 32 + (tid >> 4) * 8;
            f16x8 v;
            #pragma unroll
            for (int j = 0; j < 8; ++j) {
                const int k = kbase + j;
                const int w2row = (k < TGS_D) ? k : (k + TGS_D);
                v[j] = (f16)W2[(layer * 3 * TGS_D + w2row) * TGS_D + colg];
            }
            PW2[bb * 64 + tid] = v;
        }
    } else {
        const int l = b - 272, d = tid;
        const float* w = W2 + (l * 3 * TGS_D + TGS_D) * TGS_D;
        float acc = B2[l * TGS_D + d];
        for (int j = 0; j < TGS_D; ++j)
            acc = fmaf(__cosf(tb[j]), w[j * TGS_D + d], acc);
        tvec[l * TGS_D + d] = acc;
    }
}

// ---------------- fused per-level kernel: gather+sum -> MFMA GEMM1 -> MFMA GEMM2 ----
// 256 threads = 4 waves. Gather: one row per thread (16 threads x 16B per row).
// GEMMs: each wave owns 2 N-tiles. launch_bounds(256,2): VGPR headroom so the
// 10-deep gather load batches stay IN FLIGHT (VGPR=40 in R6 serialized them).
template<int LEVEL>
__global__ __launch_bounds__(256, 2)
void tgs_agg_kernel(
    const f16* __restrict__ NF16, const float* __restrict__ EF,
    const int* __restrict__ src_ids, const float* __restrict__ ts_arr,
    const int* __restrict__ nbr_idx,   // LEVEL1 only
    const int* __restrict__ eidx, const float* __restrict__ etime,
    const float* __restrict__ emb_in,  // LEVEL2 only (f32)
    const float* __restrict__ tw, const float* __restrict__ tb,
    const f16x8* __restrict__ PW1, const float* __restrict__ B1,
    const f16x8* __restrict__ PW2, const float* __restrict__ tvec,
    float* __restrict__ out)
{
    __shared__ f16 snf[RPB][LDA1];     // A1: [nodesum 0:128 | timesum 128:256 | edgesum 256:276 | zero pad 276:288]
    __shared__ f16 sf2[RPB][LDA2];     // A2: [src 0:128 | relusum 128:256 | pad]
    __shared__ int   s_nbr[RPB * TGS_K];
    __shared__ int   s_eid[RPB * TGS_K];
    __shared__ float s_et [RPB * TGS_K];
    __shared__ float s_ts [RPB];

    const int tid = threadIdx.x;
    const int base_row = blockIdx.x * RPB;

    // ---- stage indices / times ----
    if (tid < RPB * TGS_K) {
        if (LEVEL == 1) s_nbr[tid] = nbr_idx[base_row * TGS_K + tid];
        s_eid[tid] = eidx[base_row * TGS_K + tid];
        s_et [tid] = etime[base_row * TGS_K + tid];
    }
    if (tid < RPB)
        s_ts[tid] = (LEVEL == 1) ? ts_arr[(base_row + tid) / TGS_K] : ts_arr[base_row + tid];
    __syncthreads();

    // ---- phase 0: gather + K-sum; one row per thread, dims sub*8..sub*8+7 ----
    {
        const int sub = tid & 15;      // f16x8 slot within 128
        const int r   = tid >> 4;      // 0..15
        const int row = base_row + r;

        // neighbor-embedding K-sum: ALL 10 loads issued before any use
        float a[8] = {0.f, 0.f, 0.f, 0.f, 0.f, 0.f, 0.f, 0.f};
        if (LEVEL == 1) {
            f16x8 vv[10];
            #pragma unroll
            for (int k = 0; k < TGS_K; ++k) {
                const int nb = s_nbr[r * TGS_K + k];
                vv[k] = *(const f16x8*)(NF16 + nb * TGS_D + sub * 8);
            }
            #pragma unroll
            for (int k = 0; k < TGS_K; ++k)
                #pragma unroll
                for (int j = 0; j < 8; ++j) a[j] += (float)vv[k][j];
        } else {
            float4 t[10];
            #pragma unroll
            for (int k = 0; k < TGS_K; ++k)
                t[k] = *(const float4*)(emb_in + (row * TGS_K + k) * TGS_D + sub * 8);
            #pragma unroll
            for (int k = 0; k < TGS_K; ++k) {
                a[0] += t[k].x; a[1] += t[k].y; a[2] += t[k].z; a[3] += t[k].w;
            }
            #pragma unroll
            for (int k = 0; k < TGS_K; ++k)
                t[k] = *(const float4*)(emb_in + (row * TGS_K + k) * TGS_D + sub * 8 + 4);
            #pragma unroll
            for (int k = 0; k < TGS_K; ++k) {
                a[4] += t[k].x; a[5] += t[k].y; a[6] += t[k].z; a[7] += t[k].w;
            }
        }
        f16x8 av;
        #pragma unroll
        for (int j = 0; j < 8; ++j) av[j] = (f16)a[j];
        *(f16x8*)&snf[r][sub * 8] = av;

        // source features: straight f16 copy
        const int sid = src_ids[row];
        *(f16x8*)&sf2[r][sub * 8] = *(const f16x8*)(NF16 + sid * TGS_D + sub * 8);

        // edge-feature K-sum (threads sub 0..4); 5..7 zero the pad [276,288)
        if (sub < 5) {
            float4 ev[10];
            #pragma unroll
            for (int k = 0; k < TGS_K; ++k)
                ev[k] = ((const float4*)(EF + s_eid[r * TGS_K + k] * TGS_E))[sub];
            float4 e = make_float4(0.f, 0.f, 0.f, 0.f);
            #pragma unroll
            for (int k = 0; k < TGS_K; ++k) {
                e.x += ev[k].x; e.y += ev[k].y; e.z += ev[k].z; e.w += ev[k].w;
            }
            *(f16x4*)&snf[r][2 * TGS_D + sub * 4] = f16x4{(f16)e.x, (f16)e.y, (f16)e.z, (f16)e.w};
        } else if (sub < 8) {
            *(f16x4*)&snf[r][2 * TGS_D + sub * 4] =
                f16x4{(f16)0.f, (f16)0.f, (f16)0.f, (f16)0.f};
        }

        // edge-time-encoding K-sum: cos((ts-et)*w + b)  (VALU, overlaps loads above)
        const float4 w0 = ((const float4*)tw)[sub * 2];
        const float4 w1 = ((const float4*)tw)[sub * 2 + 1];
        const float4 b0 = ((const float4*)tb)[sub * 2];
        const float4 b1 = ((const float4*)tb)[sub * 2 + 1];
        const float ts = s_ts[r];
        float st[8] = {0.f, 0.f, 0.f, 0.f, 0.f, 0.f, 0.f, 0.f};
        #pragma unroll
        for (int k = 0; k < TGS_K; ++k) {
            const float dt = ts - s_et[r * TGS_K + k];
            st[0] += __cosf(fmaf(dt, w0.x, b0.x));
            st[1] += __cosf(fmaf(dt, w0.y, b0.y));
            st[2] += __cosf(fmaf(dt, w0.z, b0.z));
            st[3] += __cosf(fmaf(dt, w0.w, b0.w));
            st[4] += __cosf(fmaf(dt, w1.x, b1.x));
            st[5] += __cosf(fmaf(dt, w1.y, b1.y));
            st[6] += __cosf(fmaf(dt, w1.z, b1.z));
            st[7] += __cosf(fmaf(dt, w1.w, b1.w));
        }
        f16x8 sv;
        #pragma unroll
        for (int j = 0; j < 8; ++j) sv[j] = (f16)st[j];
        *(f16x8*)&snf[r][TGS_D + sub * 8] = sv;
    }
    __syncthreads();

    const int lane = tid & 63;
    const int w    = tid >> 6;         // wave id, owns N-tiles 2w, 2w+1
    const int ccol = lane & 15;        // C/D col; also A row for A-frag reads
    const int row0 = (lane >> 4) * 4;  // C/D row base

    // ---- GEMM1: h = relu(A1 @ W1 + 10*b1) -> sf2 relusum panel (f16) ----
    {
        const int t0 = 2 * w, t1 = 2 * w + 1;
        // batch-load all B-fragments (L2-hot) before the MFMA chain
        f16x8 bfa[9], bfb[9];
        #pragma unroll
        for (int kk = 0; kk < 9; ++kk) {
            bfa[kk] = PW1[(t0 * 9 + kk) * 64 + lane];
            bfb[kk] = PW1[(t1 * 9 + kk) * 64 + lane];
        }
        f32x4 acc0 = {0.f, 0.f, 0.f, 0.f}, acc1 = acc0;
        const f16* abase = &snf[ccol][(lane >> 4) * 8];
        #pragma unroll
        for (int kk = 0; kk < 9; ++kk) {
            const f16x8 af = *(const f16x8*)(abase + kk * 32);
            acc0 = __builtin_amdgcn_mfma_f32_16x16x32_f16(af, bfa[kk], acc0, 0, 0, 0);
            acc1 = __builtin_amdgcn_mfma_f32_16x16x32_f16(af, bfb[kk], acc1, 0, 0, 0);
        }
        const float b1v0 = 10.f * B1[t0 * 16 + ccol];
        const float b1v1 = 10.f * B1[t1 * 16 + ccol];
        #pragma unroll
        for (int i = 0; i < 4; ++i) {
            sf2[row0 + i][TGS_D + t0 * 16 + ccol] = (f16)fmaxf(acc0[i] + b1v0, 0.f);
            sf2[row0 + i][TGS_D + t1 * 16 + ccol] = (f16)fmaxf(acc1[i] + b1v1, 0.f);
        }
    }
    __syncthreads();

    // ---- GEMM2: out = A2 @ W2cat + tvec ----
    {
        const int t0 = 2 * w, t1 = 2 * w + 1;
        f16x8 bfa[8], bfb[8];
        #pragma unroll
        for (int kk = 0; kk < 8; ++kk) {
            bfa[kk] = PW2[(t0 * 8 + kk) * 64 + lane];
            bfb[kk] = PW2[(t1 * 8 + kk) * 64 + lane];
        }
        f32x4 acc0 = {0.f, 0.f, 0.f, 0.f}, acc1 = acc0;
        const f16* abase = &sf2[ccol][(lane >> 4) * 8];
        #pragma unroll
        for (int kk = 0; kk < 8; ++kk) {
            const f16x8 af = *(const f16x8*)(abase + kk * 32);
            acc0 = __builtin_amdgcn_mfma_f32_16x16x32_f16(af, bfa[kk], acc0, 0, 0, 0);
            acc1 = __builtin_amdgcn_mfma_f32_16x16x32_f16(af, bfb[kk], acc1, 0, 0, 0);
        }
        const float tv0 = tvec[t0 * 16 + ccol];
        const float tv1 = tvec[t1 * 16 + ccol];
        #pragma unroll
        for (int i = 0; i < 4; ++i) {
            out[(base_row + row0 + i) * TGS_D + t0 * 16 + ccol] = acc0[i] + tv0;
            out[(base_row + row0 + i) * TGS_D + t1 * 16 + ccol] = acc1[i] + tv1;
        }
    }
}

extern "C" void kernel_launch(void* const* d_in, const int* in_sizes, int n_in,
                              void* d_out, int out_size, void* d_ws, size_t ws_size,
                              hipStream_t stream) {
    const float* NF   = (const float*)d_in[0];
    const float* EF   = (const float*)d_in[1];
    const int*   SRC  = (const int*)  d_in[2];
    const float* TS   = (const float*)d_in[3];
    const int*   NBR1 = (const int*)  d_in[4];
    const int*   EI1  = (const int*)  d_in[5];
    const float* ET1  = (const float*)d_in[6];
    const int*   NBR2 = (const int*)  d_in[7];
    const int*   EI2  = (const int*)  d_in[8];
    const float* ET2  = (const float*)d_in[9];
    const float* TW   = (const float*)d_in[10];
    const float* TB   = (const float*)d_in[11];
    const float* W1   = (const float*)d_in[12];  // [2,276,128]
    const float* B1   = (const float*)d_in[13];  // [2,128]
    const float* W2   = (const float*)d_in[14];  // [2,384,128]
    const float* B2   = (const float*)d_in[15];  // [2,128]

    // workspace layout (16B-aligned offsets); total ~44.7 MiB
    float* emb1 = (float*)d_ws;                              // 40960*128*4   = 20,971,520 B
    f16*   NF16 = (f16*)((char*)d_ws + 20971520);            // 100000*128*2  = 25,600,000 B
    char*  wsb  = (char*)d_ws + 20971520 + 25600000;
    f16x8* PW1  = (f16x8*)wsb;                               // 147,456 B
    f16x8* PW2  = (f16x8*)(wsb + 147456);                    // 131,072 B
    float* tvec = (float*)(wsb + 147456 + 131072);           // 1,024 B

    tgs_nf16 <<<6250, 256, 0, stream>>>(NF, NF16);           // 12.8M elems / 8 / 256
    tgs_setup<<<274, 128, 0, stream>>>(W1, W2, TB, B2, PW1, PW2, tvec);

    const int n1 = 4096 * TGS_K;   // 40960 level-1 rows
    const int n2 = 4096;

    // Level 1 (layer-0 weights) -> emb1 (f32)
    tgs_agg_kernel<1><<<n1 / RPB, 256, 0, stream>>>(
        NF16, EF, NBR1, TS, NBR2, EI2, ET2, nullptr,
        TW, TB, PW1, B1, PW2, tvec, emb1);

    // Level 2 (layer-1 weights) -> d_out
    tgs_agg_kernel<2><<<n2 / RPB, 256, 0, stream>>>(
        NF16, EF, SRC, TS, nullptr, EI1, ET1, emb1,
        TW, TB,
        PW1 + 8 * 9 * 64, B1 + TGS_D,
        PW2 + 8 * 8 * 64, tvec + TGS_D,
        (float*)d_out);
}